// Round 1
// baseline (382.341 us; speedup 1.0000x reference)
//
#include <hip/hip_runtime.h>

// SoftDecisionTree fused pipeline for MI355X (gfx950).
// Inputs: x[16384,2048] f32, y[16384,1000] f32 one-hot, W[255,2048] f32,
//         b[255] f32, beta[255] f32, leaf_params[256,1000] f32
// Output: [loss(1) | output(16384*1000)] f32
//
// Pipeline:
//  1. prep_w:       W -> bf16 padded to 256 rows; pad b/beta
//  2. leaf_softmax: logQ = log_softmax(leaf_params), Q = exp(logQ)
//  3. find_targets: t_i = argmax_j y[i,j]
//  4. gemm_probs:   probs = sigmoid(beta*(x@W^T + b))  (bf16 MFMA, fused cvt)
//  5. tree_walk:    per-row leaf paths, node sums S0/S1, dot with logQ col, argmax leaf
//  6. finalize_loss: alpha/C regularizer + mean dot -> d_out[0]
//  7. gather_rows:  d_out[1+i*1000 ..] = Q[best_i]

typedef __attribute__((ext_vector_type(8))) short short8;
typedef __attribute__((ext_vector_type(4))) float f32x4;

#define B_ROWS 16384
#define DIM 2048
#define NCLS 1000
#define NINNER 255
#define NPAD 256

__device__ __forceinline__ unsigned cvt2bf(float a, float b) {
  // round-half-up fp32 -> bf16, packed pair
  return ((__float_as_uint(a) + 0x8000u) >> 16) | ((__float_as_uint(b) + 0x8000u) & 0xFFFF0000u);
}

__global__ __launch_bounds__(256) void prep_w(const float* __restrict__ W,
                                              const float* __restrict__ b,
                                              const float* __restrict__ beta,
                                              unsigned short* __restrict__ Wb,
                                              float* __restrict__ bp,
                                              float* __restrict__ betap) {
  int i = blockIdx.x * 256 + threadIdx.x;  // over 256*2048
  int n = i >> 11;
  float v = (n < NINNER) ? W[i] : 0.f;     // rows 0..254 are W; row 255 zero pad
  Wb[i] = (unsigned short)((__float_as_uint(v) + 0x8000u) >> 16);
  if (i < NPAD) {
    bp[i] = (i < NINNER) ? b[i] : 0.f;
    betap[i] = (i < NINNER) ? beta[i] : 0.f;
  }
}

__global__ __launch_bounds__(256) void leaf_softmax(const float* __restrict__ leaf,
                                                    float* __restrict__ logQ,
                                                    float* __restrict__ Q) {
  int l = blockIdx.x, t = threadIdx.x;
  const float* row = leaf + (size_t)l * NCLS;
  __shared__ float red[256];
  float mx = -3.4e38f;
  for (int j = t; j < NCLS; j += 256) mx = fmaxf(mx, row[j]);
  red[t] = mx; __syncthreads();
  for (int s = 128; s; s >>= 1) { if (t < s) red[t] = fmaxf(red[t], red[t + s]); __syncthreads(); }
  mx = red[0]; __syncthreads();
  float sm = 0.f;
  for (int j = t; j < NCLS; j += 256) sm += expf(row[j] - mx);
  red[t] = sm; __syncthreads();
  for (int s = 128; s; s >>= 1) { if (t < s) red[t] += red[t + s]; __syncthreads(); }
  float lse = mx + logf(red[0]);
  for (int j = t; j < NCLS; j += 256) {
    float lg = row[j] - lse;
    logQ[(size_t)l * NCLS + j] = lg;
    Q[(size_t)l * NCLS + j] = expf(lg);
  }
}

__global__ __launch_bounds__(256) void find_targets(const float* __restrict__ y,
                                                    int* __restrict__ tgt) {
  int wv = threadIdx.x >> 6, lane = threadIdx.x & 63;
  int r = blockIdx.x * 4 + wv;
  const float4* yr = (const float4*)(y + (size_t)r * NCLS);
  int found = 0x7fffffff;
#pragma unroll
  for (int i = 0; i < 4; ++i) {
    int j4 = i * 64 + lane;
    if (j4 < 250) {
      float4 v = yr[j4];
      if (v.x > 0.5f) found = min(found, 4 * j4 + 0);
      if (v.y > 0.5f) found = min(found, 4 * j4 + 1);
      if (v.z > 0.5f) found = min(found, 4 * j4 + 2);
      if (v.w > 0.5f) found = min(found, 4 * j4 + 3);
    }
  }
  for (int off = 32; off; off >>= 1) found = min(found, __shfl_down(found, off));
  if (lane == 0) tgt[r] = found;
}

// GEMM: BM=128, BN=64, BK=32; 4 waves, each computes 32x64 via 2x4 mfma tiles.
// A staged fp32->bf16 in-kernel; B (Wb) pre-converted bf16.
__global__ __launch_bounds__(256) void gemm_probs(const float* __restrict__ x,
                                                  const unsigned short* __restrict__ Wb,
                                                  const float* __restrict__ bp,
                                                  const float* __restrict__ betap,
                                                  float* __restrict__ probs) {
  __shared__ __align__(16) unsigned short As[128 * 32];
  __shared__ __align__(16) unsigned short Bs[64 * 32];
  __shared__ float ep[128 * 65];  // padded epilogue tile
  __shared__ float bsh[64], besh[64];

  int tid = threadIdx.x;
  int lane = tid & 63, wave = tid >> 6;
  int m_base = blockIdx.x * 128;
  int n_base = blockIdx.y * 64;

  if (tid < 64) { bsh[tid] = bp[n_base + tid]; besh[tid] = betap[n_base + tid]; }

  f32x4 acc[2][4] = {};

  int arow = tid >> 1, ahalf = tid & 1;
  const float* aptr = x + (size_t)(m_base + arow) * DIM + ahalf * 16;
  unsigned short* asd = &As[arow * 32 + ahalf * 16];
  int brow = tid >> 2, bseg = tid & 3;
  const unsigned short* bptr = Wb + (size_t)(n_base + brow) * DIM + bseg * 8;
  unsigned short* bsd = &Bs[brow * 32 + bseg * 8];

  int frow = lane & 15, fquad = lane >> 4;
  const unsigned short* afrag0 = &As[(wave * 32 + frow) * 32 + fquad * 8];
  const unsigned short* afrag1 = afrag0 + 16 * 32;

  for (int kt = 0; kt < DIM; kt += 32) {
    float4 v0 = *(const float4*)(aptr + kt);
    float4 v1 = *(const float4*)(aptr + kt + 4);
    float4 v2 = *(const float4*)(aptr + kt + 8);
    float4 v3 = *(const float4*)(aptr + kt + 12);
    uint4 bw = *(const uint4*)(bptr + kt);
    uint4 p0, p1;
    p0.x = cvt2bf(v0.x, v0.y); p0.y = cvt2bf(v0.z, v0.w);
    p0.z = cvt2bf(v1.x, v1.y); p0.w = cvt2bf(v1.z, v1.w);
    p1.x = cvt2bf(v2.x, v2.y); p1.y = cvt2bf(v2.z, v2.w);
    p1.z = cvt2bf(v3.x, v3.y); p1.w = cvt2bf(v3.z, v3.w);
    __syncthreads();  // previous iteration's frag reads complete
    *(uint4*)asd = p0;
    *(uint4*)(asd + 8) = p1;
    *(uint4*)bsd = bw;
    __syncthreads();
    short8 a0 = *(const short8*)afrag0;
    short8 a1 = *(const short8*)afrag1;
#pragma unroll
    for (int nt = 0; nt < 4; ++nt) {
      short8 bfr = *(const short8*)&Bs[(nt * 16 + frow) * 32 + fquad * 8];
      acc[0][nt] = __builtin_amdgcn_mfma_f32_16x16x32_bf16(a0, bfr, acc[0][nt], 0, 0, 0);
      acc[1][nt] = __builtin_amdgcn_mfma_f32_16x16x32_bf16(a1, bfr, acc[1][nt], 0, 0, 0);
    }
  }
  __syncthreads();
  // C/D layout: col = lane&15, row = (lane>>4)*4 + reg
#pragma unroll
  for (int mt = 0; mt < 2; ++mt)
#pragma unroll
    for (int nt = 0; nt < 4; ++nt)
#pragma unroll
      for (int rg = 0; rg < 4; ++rg)
        ep[(wave * 32 + mt * 16 + fquad * 4 + rg) * 65 + nt * 16 + frow] = acc[mt][nt][rg];
  __syncthreads();
  int mrow = tid >> 1, nh = (tid & 1) * 32;
  float* dst = probs + (size_t)(m_base + mrow) * NPAD + n_base + nh;
#pragma unroll
  for (int u = 0; u < 8; ++u) {
    int n0 = nh + u * 4;
    float4 o;
    o.x = 1.f / (1.f + expf(-besh[n0 + 0] * (ep[mrow * 65 + n0 + 0] + bsh[n0 + 0])));
    o.y = 1.f / (1.f + expf(-besh[n0 + 1] * (ep[mrow * 65 + n0 + 1] + bsh[n0 + 1])));
    o.z = 1.f / (1.f + expf(-besh[n0 + 2] * (ep[mrow * 65 + n0 + 2] + bsh[n0 + 2])));
    o.w = 1.f / (1.f + expf(-besh[n0 + 3] * (ep[mrow * 65 + n0 + 3] + bsh[n0 + 3])));
    *(float4*)(dst + u * 4) = o;
  }
}

// One wave per row; each lane owns 4 consecutive leaves (shared 6-level prefix).
// Node sums go to LDS (atomic), flushed once per block to global.
__global__ __launch_bounds__(256) void tree_walk(const float* __restrict__ probs,
                                                 const float* __restrict__ logQ,
                                                 const int* __restrict__ tgt,
                                                 float* __restrict__ acc,  // [S0:127][S1:127][dots:1]
                                                 int* __restrict__ best) {
  __shared__ float s0s[127], s1s[127];
  __shared__ float sdot;
  int tid = threadIdx.x;
  int lane = tid & 63, wv = tid >> 6;
  if (tid < 127) { s0s[tid] = 0.f; s1s[tid] = 0.f; }
  if (tid == 255) sdot = 0.f;
  __syncthreads();
  float wdot = 0.f;
  for (int it = 0; it < 16; ++it) {
    int r = blockIdx.x * 64 + wv * 16 + it;
    int tg = tgt[r];
    const float* pr = probs + (size_t)r * NPAD;
    const float* lq = logQ + tg;
    float pp = 1.f;  // path product into current depth
#pragma unroll
    for (int d = 1; d <= 6; ++d) {
      int pos = lane >> (7 - d);
      int idx = (1 << (d - 1)) - 1 + pos;
      float p = pr[idx];
      if ((lane & ((1 << (7 - d)) - 1)) == 0) {  // first lane covering this node
        atomicAdd(&s0s[idx], pp);
        atomicAdd(&s1s[idx], p * pp);
      }
      pp *= ((lane >> (6 - d)) & 1) ? p : (1.f - p);
    }
    float p7 = pr[63 + lane];
    atomicAdd(&s0s[63 + lane], pp);
    atomicAdd(&s1s[63 + lane], p7 * pp);
    float pL = pp * (1.f - p7), pR = pp * p7;
    float p8a = pr[127 + 2 * lane], p8b = pr[128 + 2 * lane];
    float lf0 = pL * (1.f - p8a), lf1 = pL * p8a;
    float lf2 = pR * (1.f - p8b), lf3 = pR * p8b;
    wdot += lf0 * lq[(size_t)(4 * lane + 0) * NCLS] + lf1 * lq[(size_t)(4 * lane + 1) * NCLS]
          + lf2 * lq[(size_t)(4 * lane + 2) * NCLS] + lf3 * lq[(size_t)(4 * lane + 3) * NCLS];
    float bv = lf0; int bi = 4 * lane;
    if (lf1 > bv) { bv = lf1; bi = 4 * lane + 1; }
    if (lf2 > bv) { bv = lf2; bi = 4 * lane + 2; }
    if (lf3 > bv) { bv = lf3; bi = 4 * lane + 3; }
    for (int off = 32; off; off >>= 1) {
      float ov = __shfl_down(bv, off);
      int oi = __shfl_down(bi, off);
      if (ov > bv || (ov == bv && oi < bi)) { bv = ov; bi = oi; }  // first-max tie-break
    }
    if (lane == 0) best[r] = bi;
  }
  for (int off = 32; off; off >>= 1) wdot += __shfl_down(wdot, off);
  if (lane == 0) atomicAdd(&sdot, wdot);
  __syncthreads();
  if (tid < 127) {
    atomicAdd(&acc[tid], s0s[tid]);
    atomicAdd(&acc[127 + tid], s1s[tid]);
  }
  if (tid == 255) atomicAdd(&acc[254], sdot);
}

__global__ __launch_bounds__(128) void finalize_loss(const float* __restrict__ acc,
                                                     float* __restrict__ out) {
  __shared__ float red[128];
  int t = threadIdx.x;
  float c = 0.f;
  if (t < 127) {
    float denom = acc[t];
    if (denom == 0.f) denom = 1e-6f;
    float alpha = acc[127 + t] / denom;
    alpha = fminf(fmaxf(alpha, 1e-6f), 1.f - 1e-6f);
    int d = 31 - __clz(t + 1) + 1;  // depth: idx 0 -> 1, idx 1..2 -> 2, ...
    float lm = 0.1f * exp2f(-(float)d);
    c = -lm * 0.5f * (logf(alpha) + log1pf(-alpha));
  }
  red[t] = c;
  __syncthreads();
  for (int s = 64; s; s >>= 1) { if (t < s) red[t] += red[t + s]; __syncthreads(); }
  if (t == 0) out[0] = -(acc[254] / 16384.f) + red[0];
}

__global__ __launch_bounds__(256) void gather_rows(const float* __restrict__ Q,
                                                   const int* __restrict__ best,
                                                   float* __restrict__ out) {
  int wv = threadIdx.x >> 6, lane = threadIdx.x & 63;
  int r = blockIdx.x * 4 + wv;
  const float* src = Q + (size_t)best[r] * NCLS;
  float* dst = out + 1 + (size_t)r * NCLS;  // rows start at global index 1+1000r (== 1 mod 4)
  if (lane < 3) dst[lane] = src[lane];
  if (lane == 0) dst[999] = src[999];
#pragma unroll
  for (int i = 0; i < 4; ++i) {
    int q = i * 64 + lane;
    if (q < 249) {
      int o = 3 + 4 * q;  // 16B-aligned in dst
      float4 v = make_float4(src[o], src[o + 1], src[o + 2], src[o + 3]);
      *(float4*)(dst + o) = v;
    }
  }
}

extern "C" void kernel_launch(void* const* d_in, const int* in_sizes, int n_in,
                              void* d_out, int out_size, void* d_ws, size_t ws_size,
                              hipStream_t stream) {
  const float* x = (const float*)d_in[0];
  const float* y = (const float*)d_in[1];
  const float* W = (const float*)d_in[2];
  const float* b = (const float*)d_in[3];
  const float* beta = (const float*)d_in[4];
  const float* leaf = (const float*)d_in[5];
  float* out = (float*)d_out;
  char* ws = (char*)d_ws;

  // ws layout (256B aligned): total ~19.1 MB
  unsigned short* Wb = (unsigned short*)(ws + 0);        // 256*2048*2 = 1048576
  float* bp    = (float*)(ws + 1048576);                 // 1024
  float* betap = (float*)(ws + 1049600);                 // 1024
  float* acc   = (float*)(ws + 1050624);                 // 255 floats (S0|S1|dots)
  int* tgt     = (int*)(ws + 1051648);                   // 65536
  int* best    = (int*)(ws + 1117184);                   // 65536
  float* logQ  = (float*)(ws + 1182720);                 // 1024000
  float* Q     = (float*)(ws + 2206720);                 // 1024000
  float* probs = (float*)(ws + 3230720);                 // 16384*256*4 = 16777216

  prep_w<<<2048, 256, 0, stream>>>(W, b, beta, Wb, bp, betap);
  leaf_softmax<<<256, 256, 0, stream>>>(leaf, logQ, Q);
  find_targets<<<4096, 256, 0, stream>>>(y, tgt);
  gemm_probs<<<dim3(128, 4), 256, 0, stream>>>(x, Wb, bp, betap, probs);
  hipMemsetAsync(acc, 0, 255 * sizeof(float), stream);
  tree_walk<<<256, 256, 0, stream>>>(probs, logQ, tgt, acc, best);
  finalize_loss<<<1, 128, 0, stream>>>(acc, out);
  gather_rows<<<4096, 256, 0, stream>>>(Q, best, out);
}

// Round 2
// 362.850 us; speedup vs baseline: 1.0537x; 1.0537x over previous
//
#include <hip/hip_runtime.h>

// SoftDecisionTree fused pipeline for MI355X (gfx950).
// Inputs: x[16384,2048] f32, y[16384,1000] f32 one-hot, W[255,2048] f32,
//         b[255] f32, beta[255] f32, leaf_params[256,1000] f32
// Output: [loss(1) | output(16384*1000)] f32
//
// Pipeline:
//  1. prep_w:       W -> bf16 padded to 256 rows; pad b/beta
//  2. leaf_softmax: logQT[class][leaf] = log_softmax(leaf_params)^T, Q = exp(logQ)
//  3. find_targets: t_i = argmax_j y[i,j]
//  4. gemm_xwT:     P{0,1} = x @ W^T partials (K split in 2), bf16 MFMA, fp32 out
//  5. tree_walk:    fused sigmoid epilogue + leaf paths + node sums + logQT dot + argmax
//  6. finalize_loss
//  7. gather_rows:  d_out[1+i*1000 ..] = Q[best_i]
//
// P1 scratch is carved out of d_out (overwritten by gather_rows afterwards;
// stream ordering makes this safe), keeping ws footprint == round-0 (~20 MB).

typedef __attribute__((ext_vector_type(8))) short short8;
typedef __attribute__((ext_vector_type(4))) float f32x4;

#define DIM 2048
#define NCLS 1000
#define NINNER 255
#define NPAD 256

__device__ __forceinline__ unsigned cvt2bf(float a, float b) {
  // round-half-up fp32 -> bf16, packed pair
  return ((__float_as_uint(a) + 0x8000u) >> 16) | ((__float_as_uint(b) + 0x8000u) & 0xFFFF0000u);
}

__device__ __forceinline__ void async_copy16(const unsigned short* gsrc, unsigned short* ldst) {
  __builtin_amdgcn_global_load_lds(
      (const __attribute__((address_space(1))) unsigned int*)(gsrc),
      (__attribute__((address_space(3))) unsigned int*)(ldst), 16, 0, 0);
}

__global__ __launch_bounds__(256) void prep_w(const float* __restrict__ W,
                                              const float* __restrict__ b,
                                              const float* __restrict__ beta,
                                              unsigned short* __restrict__ Wb,
                                              float* __restrict__ bp,
                                              float* __restrict__ betap) {
  int i = blockIdx.x * 256 + threadIdx.x;  // over 256*2048
  int n = i >> 11;
  float v = (n < NINNER) ? W[i] : 0.f;     // rows 0..254 are W; row 255 zero pad
  Wb[i] = (unsigned short)((__float_as_uint(v) + 0x8000u) >> 16);
  if (i < NPAD) {
    bp[i] = (i < NINNER) ? b[i] : 0.f;
    betap[i] = (i < NINNER) ? beta[i] : 0.f;
  }
}

__global__ __launch_bounds__(256) void leaf_softmax(const float* __restrict__ leaf,
                                                    float* __restrict__ logQT,
                                                    float* __restrict__ Q) {
  int l = blockIdx.x, t = threadIdx.x;
  const float* row = leaf + (size_t)l * NCLS;
  __shared__ float red[256];
  float mx = -3.4e38f;
  for (int j = t; j < NCLS; j += 256) mx = fmaxf(mx, row[j]);
  red[t] = mx; __syncthreads();
  for (int s = 128; s; s >>= 1) { if (t < s) red[t] = fmaxf(red[t], red[t + s]); __syncthreads(); }
  mx = red[0]; __syncthreads();
  float sm = 0.f;
  for (int j = t; j < NCLS; j += 256) sm += __expf(row[j] - mx);
  red[t] = sm; __syncthreads();
  for (int s = 128; s; s >>= 1) { if (t < s) red[t] += red[t + s]; __syncthreads(); }
  float lse = mx + __logf(red[0]);
  for (int j = t; j < NCLS; j += 256) {
    float lg = row[j] - lse;
    logQT[(size_t)j * NPAD + l] = lg;      // transposed: [class][leaf]
    Q[(size_t)l * NCLS + j] = __expf(lg);
  }
}

__global__ __launch_bounds__(256) void find_targets(const float* __restrict__ y,
                                                    int* __restrict__ tgt) {
  int wv = threadIdx.x >> 6, lane = threadIdx.x & 63;
  int r = blockIdx.x * 4 + wv;
  const float4* yr = (const float4*)(y + (size_t)r * NCLS);
  int found = 0x7fffffff;
#pragma unroll
  for (int i = 0; i < 4; ++i) {
    int j4 = i * 64 + lane;
    if (j4 < 250) {
      float4 v = yr[j4];
      if (v.x > 0.5f) found = min(found, 4 * j4 + 0);
      if (v.y > 0.5f) found = min(found, 4 * j4 + 1);
      if (v.z > 0.5f) found = min(found, 4 * j4 + 2);
      if (v.w > 0.5f) found = min(found, 4 * j4 + 3);
    }
  }
  for (int off = 32; off; off >>= 1) found = min(found, __shfl_down(found, off));
  if (lane == 0) tgt[r] = found;
}

// GEMM: BM=128, BN=128, BK=32, K split in 2 (blockIdx.z), grid 128x2x2 = 512 blocks.
// 4 waves in 2x2; each wave computes 64x64 via 4x4 mfma tiles (16 MFMA / k-step).
// A fp32->bf16 fused staging; B bf16 via global_load_lds (16B).
__global__ __launch_bounds__(256, 2) void gemm_xwT(const float* __restrict__ x,
                                                   const unsigned short* __restrict__ Wb,
                                                   float* __restrict__ P0,
                                                   float* __restrict__ P1) {
  __shared__ __align__(16) unsigned short As[128 * 40];  // padded stride 40 (bank-safe)
  __shared__ __align__(16) unsigned short Bs[128 * 32];  // unpadded (global_load_lds order)

  int tid = threadIdx.x;
  int lane = tid & 63, wave = tid >> 6;
  int m_base = blockIdx.x * 128;
  int n_base = blockIdx.y * 128;
  int k_base = blockIdx.z * 1024;
  float* P = blockIdx.z ? P1 : P0;

  f32x4 acc[4][4] = {};

  // A staging: thread t loads 16 floats of row (t>>1), k-half (t&1)
  int arow = tid >> 1, aseg = tid & 1;
  const float* aptr = x + (size_t)(m_base + arow) * DIM + k_base + aseg * 16;
  unsigned short* asd = &As[arow * 40 + aseg * 16];

  // B staging: wave stages two 16-col chunks per k-step via global_load_lds
  int ci0 = wave * 2, ci1 = wave * 2 + 1;
  const unsigned short* bg0 =
      Wb + (size_t)(n_base + ci0 * 16 + (lane >> 2)) * DIM + k_base + (lane & 3) * 8;
  const unsigned short* bg1 = bg0 + (size_t)16 * DIM;
  unsigned short* bl0 = &Bs[ci0 * 512];
  unsigned short* bl1 = &Bs[ci1 * 512];

  int frow = lane & 15, fquad = lane >> 4;
  int wrow = (wave & 1) * 64;   // wave m offset
  int wcol = (wave >> 1) * 64;  // wave n offset

  for (int kt = 0; kt < 1024; kt += 32) {
    const float4* ap = (const float4*)(aptr + kt);
    float4 v0 = ap[0], v1 = ap[1], v2 = ap[2], v3 = ap[3];
    uint4 p0, p1;
    p0.x = cvt2bf(v0.x, v0.y); p0.y = cvt2bf(v0.z, v0.w);
    p0.z = cvt2bf(v1.x, v1.y); p0.w = cvt2bf(v1.z, v1.w);
    p1.x = cvt2bf(v2.x, v2.y); p1.y = cvt2bf(v2.z, v2.w);
    p1.z = cvt2bf(v3.x, v3.y); p1.w = cvt2bf(v3.z, v3.w);
    __syncthreads();  // previous iteration's frag reads complete
    *(uint4*)asd = p0;
    *(uint4*)(asd + 8) = p1;
    async_copy16(bg0 + kt, bl0);
    async_copy16(bg1 + kt, bl1);
    __syncthreads();  // vmcnt(0) drain makes global_load_lds data visible
    short8 a[4];
#pragma unroll
    for (int mt = 0; mt < 4; ++mt)
      a[mt] = *(const short8*)&As[(wrow + mt * 16 + frow) * 40 + fquad * 8];
#pragma unroll
    for (int nt = 0; nt < 4; ++nt) {
      short8 bb = *(const short8*)&Bs[(wcol + nt * 16 + frow) * 32 + fquad * 8];
#pragma unroll
      for (int mt = 0; mt < 4; ++mt)
        acc[mt][nt] = __builtin_amdgcn_mfma_f32_16x16x32_bf16(a[mt], bb, acc[mt][nt], 0, 0, 0);
    }
  }
  // C/D layout: col = lane&15 (n), row = (lane>>4)*4 + reg (m). Store raw fp32 partials.
#pragma unroll
  for (int mt = 0; mt < 4; ++mt) {
#pragma unroll
    for (int rg = 0; rg < 4; ++rg) {
      float* dst = P + (size_t)(m_base + wrow + mt * 16 + fquad * 4 + rg) * NPAD + n_base + wcol + frow;
#pragma unroll
      for (int nt = 0; nt < 4; ++nt) dst[nt * 16] = acc[mt][nt][rg];
    }
  }
}

// 1024 blocks x 4 waves x 4 rows. Fused epilogue: p = sigmoid(beta*(P0+P1+b)) staged
// per-wave in LDS, then tree math, node sums S0/S1 (LDS atomics), logQT float4 dot,
// argmax leaf.
__global__ __launch_bounds__(256) void tree_walk(const float* __restrict__ P0,
                                                 const float* __restrict__ P1,
                                                 const float* __restrict__ bp,
                                                 const float* __restrict__ betap,
                                                 const float* __restrict__ logQT,
                                                 const int* __restrict__ tgt,
                                                 float* __restrict__ acc,  // [S0:127][S1:127][dot:1]
                                                 int* __restrict__ best) {
  __shared__ float ws[4][256];
  __shared__ float s0s[127], s1s[127];
  __shared__ float sdot;
  int tid = threadIdx.x;
  int lane = tid & 63, wv = tid >> 6;
  if (tid < 127) { s0s[tid] = 0.f; s1s[tid] = 0.f; }
  if (tid == 255) sdot = 0.f;
  __syncthreads();
  float4 bb = *(const float4*)(bp + lane * 4);
  float4 be = *(const float4*)(betap + lane * 4);
  float* wsp = ws[wv];
  float wdot = 0.f;
  for (int it = 0; it < 4; ++it) {
    int r = blockIdx.x * 16 + wv * 4 + it;
    float4 u = *(const float4*)(P0 + (size_t)r * NPAD + lane * 4);
    float4 v = *(const float4*)(P1 + (size_t)r * NPAD + lane * 4);
    float4 pz;
    pz.x = 1.f / (1.f + __expf(-be.x * (u.x + v.x + bb.x)));
    pz.y = 1.f / (1.f + __expf(-be.y * (u.y + v.y + bb.y)));
    pz.z = 1.f / (1.f + __expf(-be.z * (u.z + v.z + bb.z)));
    pz.w = 1.f / (1.f + __expf(-be.w * (u.w + v.w + bb.w)));
    *(float4*)(wsp + lane * 4) = pz;
    __asm__ volatile("" ::: "memory");  // keep LDS write before cross-lane LDS reads
    int tg = tgt[r];
    float pp = 1.f;  // path product into current depth
#pragma unroll
    for (int d = 1; d <= 6; ++d) {
      int idx = (1 << (d - 1)) - 1 + (lane >> (7 - d));
      float p = wsp[idx];
      if ((lane & ((1 << (7 - d)) - 1)) == 0) {  // first lane covering this node
        atomicAdd(&s0s[idx], pp);
        atomicAdd(&s1s[idx], p * pp);
      }
      pp *= ((lane >> (6 - d)) & 1) ? p : (1.f - p);
    }
    float p7 = wsp[63 + lane];
    atomicAdd(&s0s[63 + lane], pp);
    atomicAdd(&s1s[63 + lane], p7 * pp);
    float pL = pp * (1.f - p7), pR = pp * p7;
    float p8a = wsp[127 + 2 * lane], p8b = wsp[128 + 2 * lane];
    float lf0 = pL * (1.f - p8a), lf1 = pL * p8a;
    float lf2 = pR * (1.f - p8b), lf3 = pR * p8b;
    float4 lq = *(const float4*)(logQT + (size_t)tg * NPAD + lane * 4);
    wdot += lf0 * lq.x + lf1 * lq.y + lf2 * lq.z + lf3 * lq.w;
    float bv = lf0; int bi = 4 * lane;
    if (lf1 > bv) { bv = lf1; bi = 4 * lane + 1; }
    if (lf2 > bv) { bv = lf2; bi = 4 * lane + 2; }
    if (lf3 > bv) { bv = lf3; bi = 4 * lane + 3; }
    for (int off = 32; off; off >>= 1) {
      float ov = __shfl_down(bv, off);
      int oi = __shfl_down(bi, off);
      if (ov > bv || (ov == bv && oi < bi)) { bv = ov; bi = oi; }  // first-max tie-break
    }
    if (lane == 0) best[r] = bi;
  }
  for (int off = 32; off; off >>= 1) wdot += __shfl_down(wdot, off);
  if (lane == 0) atomicAdd(&sdot, wdot);
  __syncthreads();
  if (tid < 127) {
    atomicAdd(&acc[tid], s0s[tid]);
    atomicAdd(&acc[127 + tid], s1s[tid]);
  }
  if (tid == 255) atomicAdd(&acc[254], sdot);
}

__global__ __launch_bounds__(128) void finalize_loss(const float* __restrict__ acc,
                                                     float* __restrict__ out) {
  __shared__ float red[128];
  int t = threadIdx.x;
  float c = 0.f;
  if (t < 127) {
    float denom = acc[t];
    if (denom == 0.f) denom = 1e-6f;
    float alpha = acc[127 + t] / denom;
    alpha = fminf(fmaxf(alpha, 1e-6f), 1.f - 1e-6f);
    int d = 31 - __clz(t + 1) + 1;  // depth: idx 0 -> 1, idx 1..2 -> 2, ...
    float lm = 0.1f * exp2f(-(float)d);
    c = -lm * 0.5f * (logf(alpha) + log1pf(-alpha));
  }
  red[t] = c;
  __syncthreads();
  for (int s = 64; s; s >>= 1) { if (t < s) red[t] += red[t + s]; __syncthreads(); }
  if (t == 0) out[0] = -(acc[254] / 16384.f) + red[0];
}

__global__ __launch_bounds__(256) void gather_rows(const float* __restrict__ Q,
                                                   const int* __restrict__ best,
                                                   float* __restrict__ out) {
  int wv = threadIdx.x >> 6, lane = threadIdx.x & 63;
  int r = blockIdx.x * 4 + wv;
  const float* src = Q + (size_t)best[r] * NCLS;
  float* dst = out + 1 + (size_t)r * NCLS;  // rows start at global index 1+1000r
  if (lane < 3) dst[lane] = src[lane];
  if (lane == 0) dst[999] = src[999];
#pragma unroll
  for (int i = 0; i < 4; ++i) {
    int q = i * 64 + lane;
    if (q < 249) {
      int o = 3 + 4 * q;  // 16B-aligned in dst
      float4 v = make_float4(src[o], src[o + 1], src[o + 2], src[o + 3]);
      *(float4*)(dst + o) = v;
    }
  }
}

extern "C" void kernel_launch(void* const* d_in, const int* in_sizes, int n_in,
                              void* d_out, int out_size, void* d_ws, size_t ws_size,
                              hipStream_t stream) {
  const float* x = (const float*)d_in[0];
  const float* y = (const float*)d_in[1];
  const float* W = (const float*)d_in[2];
  const float* b = (const float*)d_in[3];
  const float* beta = (const float*)d_in[4];
  const float* leaf = (const float*)d_in[5];
  float* out = (float*)d_out;
  char* ws = (char*)d_ws;

  // ws layout (same ~20 MB footprint as round 0)
  unsigned short* Wb = (unsigned short*)(ws + 0);        // 1048576
  float* bp    = (float*)(ws + 1048576);                 // 1024
  float* betap = (float*)(ws + 1049600);                 // 1024
  float* acc   = (float*)(ws + 1050624);                 // 1024 (255 used)
  int* tgt     = (int*)(ws + 1051648);                   // 65536
  int* best    = (int*)(ws + 1117184);                   // 65536
  float* logQT = (float*)(ws + 1182720);                 // 1000*256*4 = 1024000
  float* Q     = (float*)(ws + 2206720);                 // 1024000
  float* P0    = (float*)(ws + 3230720);                 // 16384*256*4 = 16777216
  float* P1    = out + 4;                                // scratch in d_out (16B-aligned),
                                                         // consumed before gather_rows overwrites

  prep_w<<<2048, 256, 0, stream>>>(W, b, beta, Wb, bp, betap);
  leaf_softmax<<<256, 256, 0, stream>>>(leaf, logQT, Q);
  find_targets<<<4096, 256, 0, stream>>>(y, tgt);
  gemm_xwT<<<dim3(128, 2, 2), 256, 0, stream>>>(x, Wb, P0, P1);
  hipMemsetAsync(acc, 0, 256 * sizeof(float), stream);
  tree_walk<<<1024, 256, 0, stream>>>(P0, P1, bp, betap, logQT, tgt, acc, best);
  finalize_loss<<<1, 128, 0, stream>>>(acc, out);
  gather_rows<<<4096, 256, 0, stream>>>(Q, best, out);
}